// Round 4
// baseline (1098.843 us; speedup 1.0000x reference)
//
#include <hip/hip_runtime.h>
#include <stdint.h>

// Problem: B=64, T=128, F=1024, H=1024. x:[64,128,1024] f32, W:[2048,4096] f32, b:[4096] f32.
// out:[64,128,1024] f32.
#define BATCH 64
#define TSEQ  128
#define FDIM  1024
#define HDIM  1024
#define GDIM  4096              // 4H
#define MROWS 8192              // BATCH*TSEQ
#define NB    128               // persistent blocks in recurrent phase (co-resident on 256 CUs)

typedef short bf16x8 __attribute__((ext_vector_type(8)));   // 8 bf16 in 4 VGPRs
typedef float f32x4  __attribute__((ext_vector_type(4)));

__device__ __forceinline__ unsigned short f2bf(float f) {
    union { float f; uint32_t u; } v; v.f = f;
    uint32_t u = v.u;
    return (unsigned short)((u + 0x7FFFu + ((u >> 16) & 1u)) >> 16);  // RNE
}
__device__ __forceinline__ float bf2f(unsigned short h) {
    union { uint32_t u; float f; } v; v.u = ((uint32_t)h) << 16; return v.f;
}
__device__ __forceinline__ float sigmoidf_(float x) { return 1.f / (1.f + __expf(-x)); }
__device__ __forceinline__ float tanhf_(float x)    { return 2.f / (1.f + __expf(-2.f * x)) - 1.f; }

union SP { short s[8]; int4 v; };
union UU { int4 i; bf16x8 v; };

// L2-bypass 8B store (relaxed agent atomic -> global_store_dwordx2 sc0 sc1, lands at IF).
__device__ __forceinline__ void st64cc(void* p, unsigned long long v) {
    __hip_atomic_store((unsigned long long*)p, v, __ATOMIC_RELAXED, __HIP_MEMORY_SCOPE_AGENT);
}
// L2-bypass 4B store (flag signal).
__device__ __forceinline__ void st32cc(void* p, uint32_t v) {
    __hip_atomic_store((uint32_t*)p, v, __ATOMIC_RELAXED, __HIP_MEMORY_SCOPE_AGENT);
}

// ---------------- init: zero flags + h slot 0 ----------------
__global__ void k_init(uint32_t* p, int nwords) {
    int i = blockIdx.x * blockDim.x + threadIdx.x;
    int s = gridDim.x * blockDim.x;
    for (; i < nwords; i += s) p[i] = 0;
}

// ---------------- W fp32 [2048][4096] -> WxT hi/lo bf16 [4096][1024], WhT bf16 [4096][1024] ----
__global__ void k_tw(const float* __restrict__ W,
                     unsigned short* __restrict__ wxth, unsigned short* __restrict__ wxtl,
                     unsigned short* __restrict__ wht) {
    __shared__ float tile[64 * 65];
    const int nb = blockIdx.x;      // 0..63  (n tiles)
    const int kb = blockIdx.y;      // 0..31  (k tiles over 2048)
    const int t  = threadIdx.x;
    const int col = t & 63, rg = t >> 6;
#pragma unroll
    for (int i = 0; i < 16; i++) {
        int row = rg * 16 + i;
        tile[row * 65 + col] = W[(size_t)(kb * 64 + row) * 4096 + nb * 64 + col];
    }
    __syncthreads();
    if (kb < 16) {
        const int kbase = kb * 64;
#pragma unroll
        for (int i = 0; i < 16; i++) {
            int rp = rg * 16 + i;                      // n index within tile
            float v = tile[col * 65 + rp];             // = W[kb*64+col][nb*64+rp]
            unsigned short h = f2bf(v);
            size_t idx = (size_t)(nb * 64 + rp) * 1024 + kbase + col;
            wxth[idx] = h;
            wxtl[idx] = f2bf(v - bf2f(h));
        }
    } else {
        const int kbase = (kb - 16) * 64;
#pragma unroll
        for (int i = 0; i < 16; i++) {
            int rp = rg * 16 + i;
            float v = tile[col * 65 + rp];
            wht[(size_t)(nb * 64 + rp) * 1024 + kbase + col] = f2bf(v);
        }
    }
}

// ---------------- GEMM1: xz_f32[8192][4096] = x[8192][1024] @ Wx, split-bf16 (3-MFMA) ---------
__global__ __launch_bounds__(256) void k_gemm1(const float* __restrict__ Xf,
                                               const unsigned short* __restrict__ WxTh,
                                               const unsigned short* __restrict__ WxTl,
                                               float* __restrict__ xz) {
    __shared__ short Ash[128 * 40];   // stride 40 elems (80B) -> 2-way banks (free)
    __shared__ short Asl[128 * 40];
    __shared__ short Bsh[128 * 40];
    __shared__ short Bsl[128 * 40];
    const int n0 = blockIdx.x * 128;
    const int m0 = blockIdx.y * 128;
    const int t = threadIdx.x;
    const int wave = t >> 6, lane = t & 63;
    const int wm = wave >> 1, wn = wave & 1;
    const int q = lane >> 4, cl = lane & 15;
    const int row_a = t >> 2;            // 0..63
    const int kc = (t & 3) * 8;          // 8-elem chunk within the 32-elem k-slab

    f32x4 acc[4][4];
#pragma unroll
    for (int i = 0; i < 4; i++)
#pragma unroll
        for (int j = 0; j < 4; j++) acc[i][j] = (f32x4){0.f, 0.f, 0.f, 0.f};

    for (int kb = 0; kb < 32; kb++) {
        const int k0 = kb * 32;
        float va0[8], va1[8];
        {
            const float* p0 = Xf + (size_t)(m0 + row_a) * 1024 + k0 + kc;
            const float* p1 = Xf + (size_t)(m0 + 64 + row_a) * 1024 + k0 + kc;
            *(float4*)(va0)     = *(const float4*)(p0);
            *(float4*)(va0 + 4) = *(const float4*)(p0 + 4);
            *(float4*)(va1)     = *(const float4*)(p1);
            *(float4*)(va1 + 4) = *(const float4*)(p1 + 4);
        }
        int4 bh0 = *(const int4*)(WxTh + (size_t)(n0 + row_a)      * 1024 + k0 + kc);
        int4 bh1 = *(const int4*)(WxTh + (size_t)(n0 + 64 + row_a) * 1024 + k0 + kc);
        int4 bl0 = *(const int4*)(WxTl + (size_t)(n0 + row_a)      * 1024 + k0 + kc);
        int4 bl1 = *(const int4*)(WxTl + (size_t)(n0 + 64 + row_a) * 1024 + k0 + kc);
        __syncthreads();
        {
            SP h0, l0, h1, l1;
#pragma unroll
            for (int i = 0; i < 8; i++) {
                unsigned short h = f2bf(va0[i]);
                h0.s[i] = (short)h; l0.s[i] = (short)f2bf(va0[i] - bf2f(h));
                unsigned short g = f2bf(va1[i]);
                h1.s[i] = (short)g; l1.s[i] = (short)f2bf(va1[i] - bf2f(g));
            }
            *(int4*)(Ash + row_a * 40 + kc)        = h0.v;
            *(int4*)(Asl + row_a * 40 + kc)        = l0.v;
            *(int4*)(Ash + (64 + row_a) * 40 + kc) = h1.v;
            *(int4*)(Asl + (64 + row_a) * 40 + kc) = l1.v;
        }
        *(int4*)(Bsh + row_a * 40 + kc)        = bh0;
        *(int4*)(Bsh + (64 + row_a) * 40 + kc) = bh1;
        *(int4*)(Bsl + row_a * 40 + kc)        = bl0;
        *(int4*)(Bsl + (64 + row_a) * 40 + kc) = bl1;
        __syncthreads();
        bf16x8 ah[4], al[4], bh[4], bl[4];
#pragma unroll
        for (int i = 0; i < 4; i++) {
            ah[i] = *(const bf16x8*)(Ash + (wm * 64 + i * 16 + cl) * 40 + q * 8);
            al[i] = *(const bf16x8*)(Asl + (wm * 64 + i * 16 + cl) * 40 + q * 8);
        }
#pragma unroll
        for (int j = 0; j < 4; j++) {
            bh[j] = *(const bf16x8*)(Bsh + (wn * 64 + j * 16 + cl) * 40 + q * 8);
            bl[j] = *(const bf16x8*)(Bsl + (wn * 64 + j * 16 + cl) * 40 + q * 8);
        }
#pragma unroll
        for (int i = 0; i < 4; i++)
#pragma unroll
            for (int j = 0; j < 4; j++) {
                acc[i][j] = __builtin_amdgcn_mfma_f32_16x16x32_bf16(ah[i], bh[j], acc[i][j], 0, 0, 0);
                acc[i][j] = __builtin_amdgcn_mfma_f32_16x16x32_bf16(al[i], bh[j], acc[i][j], 0, 0, 0);
                acc[i][j] = __builtin_amdgcn_mfma_f32_16x16x32_bf16(ah[i], bl[j], acc[i][j], 0, 0, 0);
            }
    }
    // epilogue: C/D layout col=lane&15, row=q*4+reg; write fp32
#pragma unroll
    for (int i = 0; i < 4; i++) {
#pragma unroll
        for (int j = 0; j < 4; j++) {
            int gm = m0 + wm * 64 + i * 16 + q * 4;
            int gn = n0 + wn * 64 + j * 16 + cl;
#pragma unroll
            for (int r = 0; r < 4; r++)
                xz[(size_t)(gm + r) * 4096 + gn] = acc[i][j][r];
        }
    }
}

// ---------------- persistent recurrent kernel ----------------
// NB=128 blocks x 256 thr. Block owns 8 h-cols -> 32 gate cols [i(8) j(8) | f(8) o(8)].
// h exchange: ROTATING buffer (write-once addresses); producers bypass-store to IF,
// consumers normal cached loads. Signal: distributed per-producer write-once flags,
// GROUPED BY XCD: producer blk -> flag idx (blk&7)*16 + (blk>>3); group g (= XCD g)
// produces h cols [128g, 128g+128) = K-chunk g of the Wh GEMM (4 MFMA iters).
// Chunked dataflow — consumers process each K-chunk as soon as its 16 producer flags
// are set, instead of a full 128-flag barrier. Straggler spread overlaps the GEMM
// instead of serializing with it. Line-safety: each 64B hrot line is written only by
// producers of one group and demand-fetched only post-flag.
// (Resubmit of round-3 source: bench infra failed twice with no kernel error; audit
// found no deadlock — dependency structure identical to verified full-barrier version.)
__global__ __launch_bounds__(256, 1) void k_rnn(const float* __restrict__ xz,
                                                const unsigned short* __restrict__ WhT,
                                                const float* __restrict__ bias,
                                                unsigned short* hrot,       // 129 x [64][1024] bf16
                                                int* flags,                 // TSEQ x NB ints, write-once
                                                float* __restrict__ out) {
    __shared__ short Ws[32 * 1024];     // 64 KB
    __shared__ short hs[64 * 8];        // h transpose staging, 1 KB
    const int t = threadIdx.x;
    const int blk = blockIdx.x;
    // XCD-grouped columns: blocks blk&7==x own cols [x*128, x*128+128)
    const int n0 = (((blk & 7) << 4) | (blk >> 3)) * 8;
    const int wave = t >> 6, lane = t & 63;
    const int q = lane >> 4, cl = lane & 15;
    const int m = wave * 16 + cl;       // A-fragment row (batch)

    // preload Wh slice into LDS: vcol = g*8+cc -> WhT row g*1024+n0+cc
    {
        const int vcol = t >> 3;            // 0..31
        const int part = t & 7;             // 0..7
        const int g = vcol >> 3, cc2 = vcol & 7, swl = vcol & 7;
        const unsigned short* src = WhT + (size_t)(g * 1024 + n0 + cc2) * 1024;
        short* dstrow = Ws + vcol * 1024;
#pragma unroll
        for (int i = 0; i < 16; i++) {
            int kch = part * 16 + i;        // 16B chunk id 0..127
            int4 v = *(const int4*)(src + kch * 8);
            *(int4*)(dstrow + ((kch ^ swl) * 8)) = v;
        }
    }
    const int cc = cl & 7;
    const bool act = (cl < 8);
    float bi = 0.f, bj = 0.f, bfv = 0.f, bo = 0.f;
    if (act) {
        bi  = bias[n0 + cc];
        bj  = bias[1024 + n0 + cc];
        bfv = bias[2048 + n0 + cc];
        bo  = bias[3072 + n0 + cc];
    }
    float c[4] = {0.f, 0.f, 0.f, 0.f};
    const int sw = cl & 7;
    // all 4 waves poll: lane l covers flag words 2l,2l+1 (8B); lanes 8g..8g+7 cover group g.
    // own block's flag OR'd in locally (no IF round trip for it).
    const int idx_self = ((blk & 7) << 4) | (blk >> 3);
    const unsigned long long selfmask =
        ((t & 63) == (idx_self >> 1)) ? ((idx_self & 1) ? (1ULL << 32) : 1ULL) : 0ULL;
    __syncthreads();

    for (int tt = 0; tt < TSEQ; tt++) {
        // prefetch xz for this step (independent of other blocks' h) — ISSUE BEFORE polling
        float pxi[4], pxj[4], pxf[4], pxo[4];
        if (act) {
#pragma unroll
            for (int r = 0; r < 4; r++) {
                int m2 = wave * 16 + q * 4 + r;
                const float* xp = xz + (size_t)(m2 * 128 + tt) * 4096 + n0 + cc;
                pxi[r] = xp[0];
                pxj[r] = xp[1024];
                pxf[r] = xp[2048];
                pxo[r] = xp[3072];
            }
        }
        __builtin_amdgcn_sched_barrier(0);   // pin: prefetch issued before poll/chunk loop

        const char* ab = (const char*)hrot + (size_t)tt * 131072 + (size_t)m * 2048 + q * 16;
        const unsigned long long* fbase =
            (const unsigned long long*)flags + (size_t)(tt - 1) * 64 + (t & 63);

        f32x4 acc0a = (f32x4){0.f, 0.f, 0.f, 0.f};
        f32x4 acc0b = (f32x4){0.f, 0.f, 0.f, 0.f};
        f32x4 acc1a = (f32x4){0.f, 0.f, 0.f, 0.f};
        f32x4 acc1b = (f32x4){0.f, 0.f, 0.f, 0.f};

        unsigned done = 0;
        while (done != 0xFFu) {
            unsigned ready;
            if (tt == 0) {
                ready = 0xFFu;                 // slot 0 is pre-zeroed; no producers
            } else {
                unsigned long long v =
                    __hip_atomic_load(fbase, __ATOMIC_RELAXED, __HIP_MEMORY_SCOPE_AGENT);
                unsigned long long x = __ballot((v | selfmask) == 0x0000000100000001ULL);
                x &= x >> 1; x &= x >> 2; x &= x >> 4;   // bit 8g = AND of lanes 8g..8g+7
                ready = 0;
#pragma unroll
                for (int g2 = 0; g2 < 8; g2++)
                    ready |= (unsigned)((x >> (8 * g2)) & 1ULL) << g2;
            }
            unsigned avail = ready & ~done;
            while (avail) {
                const int g = __builtin_ctz(avail);
                avail &= avail - 1;
                done |= 1u << g;
                __atomic_signal_fence(__ATOMIC_ACQUIRE);   // no hoisting of h loads above flag check
                // h chunk g: k-dims [128g,128g+128) -> 4 int4 per lane
                UU a0, a1, a2, a3;
                a0.i = *(const int4*)(ab + (4 * g + 0) * 64);
                a1.i = *(const int4*)(ab + (4 * g + 1) * 64);
                a2.i = *(const int4*)(ab + (4 * g + 2) * 64);
                a3.i = *(const int4*)(ab + (4 * g + 3) * 64);
                const int ch0 = ((4 * g + 0) * 4 + q) ^ sw;
                const int ch1 = ((4 * g + 1) * 4 + q) ^ sw;
                const int ch2 = ((4 * g + 2) * 4 + q) ^ sw;
                const int ch3 = ((4 * g + 3) * 4 + q) ^ sw;
                bf16x8 b00 = *(const bf16x8*)(Ws + cl * 1024 + ch0 * 8);
                bf16x8 b10 = *(const bf16x8*)(Ws + (16 + cl) * 1024 + ch0 * 8);
                bf16x8 b01 = *(const bf16x8*)(Ws + cl * 1024 + ch1 * 8);
                bf16x8 b11 = *(const bf16x8*)(Ws + (16 + cl) * 1024 + ch1 * 8);
                acc0a = __builtin_amdgcn_mfma_f32_16x16x32_bf16(a0.v, b00, acc0a, 0, 0, 0);
                acc1a = __builtin_amdgcn_mfma_f32_16x16x32_bf16(a0.v, b10, acc1a, 0, 0, 0);
                acc0b = __builtin_amdgcn_mfma_f32_16x16x32_bf16(a1.v, b01, acc0b, 0, 0, 0);
                acc1b = __builtin_amdgcn_mfma_f32_16x16x32_bf16(a1.v, b11, acc1b, 0, 0, 0);
                bf16x8 b02 = *(const bf16x8*)(Ws + cl * 1024 + ch2 * 8);
                bf16x8 b12 = *(const bf16x8*)(Ws + (16 + cl) * 1024 + ch2 * 8);
                bf16x8 b03 = *(const bf16x8*)(Ws + cl * 1024 + ch3 * 8);
                bf16x8 b13 = *(const bf16x8*)(Ws + (16 + cl) * 1024 + ch3 * 8);
                acc0a = __builtin_amdgcn_mfma_f32_16x16x32_bf16(a2.v, b02, acc0a, 0, 0, 0);
                acc1a = __builtin_amdgcn_mfma_f32_16x16x32_bf16(a2.v, b12, acc1a, 0, 0, 0);
                acc0b = __builtin_amdgcn_mfma_f32_16x16x32_bf16(a3.v, b03, acc0b, 0, 0, 0);
                acc1b = __builtin_amdgcn_mfma_f32_16x16x32_bf16(a3.v, b13, acc1b, 0, 0, 0);
            }
        }
        f32x4 acc0 = acc0a + acc0b;
        f32x4 acc1 = acc1a + acc1b;
        // gate math: lane (q,cl<8) row-group q*4+r, col cc; zj/zo live in lane^8
        float zi[4], zj[4], zf[4], zo[4];
#pragma unroll
        for (int r = 0; r < 4; r++) {
            float a0 = acc0[r], a1 = acc1[r];
            float a0x = __shfl_xor(a0, 8);
            float a1x = __shfl_xor(a1, 8);
            zi[r] = a0; zj[r] = a0x; zf[r] = a1; zo[r] = a1x;
        }
        float hv4[4];
        if (act) {
#pragma unroll
            for (int r = 0; r < 4; r++) {
                float vi = zi[r] + pxi[r] + bi;
                float vj = zj[r] + pxj[r] + bj;
                float vf = zf[r] + pxf[r] + bfv + 1.0f;    // forget bias
                float vo = zo[r] + pxo[r] + bo;
                float cn = c[r] * sigmoidf_(vf) + sigmoidf_(vi) * tanhf_(vj);
                c[r] = cn;
                float h = tanhf_(cn) * sigmoidf_(vo);
                hv4[r] = h;
                hs[(wave * 16 + q * 4 + r) * 8 + cc] = (short)f2bf(h);
            }
        }
        __syncthreads();   // hs visible to all waves
        if (t < 128) {
            // row = t>>1 (0..63), half = t&1; 8B per store
            unsigned long long hv = *(const unsigned long long*)(hs + (t >> 1) * 8 + (t & 1) * 4);
            st64cc((char*)hrot + (size_t)(tt + 1) * 131072 + (size_t)(t >> 1) * 2048 + n0 * 2 + (t & 1) * 8, hv);
        }
        __syncthreads();   // vmcnt(0): h row-stores ACK'd at IF before signal
        if (t == 0) st32cc(flags + (size_t)tt * NB + idx_self, 1u);
        // out stores AFTER the signal — off the pre-signal drain critical path
        if (act) {
#pragma unroll
            for (int r = 0; r < 4; r++) {
                int m2 = wave * 16 + q * 4 + r;
                out[(size_t)(m2 * 128 + tt) * 1024 + n0 + cc] = hv4[r];
            }
        }
    }
}

// ---------------- launch ----------------
extern "C" void kernel_launch(void* const* d_in, const int* in_sizes, int n_in,
                              void* d_out, int out_size, void* d_ws, size_t ws_size,
                              hipStream_t stream) {
    const float* x = (const float*)d_in[0];
    const float* W = (const float*)d_in[1];
    const float* b = (const float*)d_in[2];
    float* out = (float*)d_out;
    char* ws = (char*)d_ws;

    // workspace layout (bytes):
    unsigned short* WXTH = (unsigned short*)(ws);                              // 8 MB
    unsigned short* WXTL = (unsigned short*)(ws + (size_t)8  * 1024 * 1024);   // 8 MB
    unsigned short* WHT  = (unsigned short*)(ws + (size_t)16 * 1024 * 1024);   // 8 MB
    float*          XZ   = (float*)         (ws + (size_t)24 * 1024 * 1024);   // 128 MB fp32
    int*            FLAGS= (int*)           (ws + (size_t)152 * 1024 * 1024);  // 64 KB (TSEQ*NB)
    unsigned short* HROT = (unsigned short*)(ws + (size_t)152 * 1024 * 1024 + 65536); // 129*128KB

    // zero FLAGS (64 KB) + HROT slot 0 (128 KB) = 196608 B = 49152 words
    k_init<<<256, 256, 0, stream>>>((uint32_t*)FLAGS, 49152);
    dim3 gtw(64, 32);
    k_tw<<<gtw, 256, 0, stream>>>(W, WXTH, WXTL, WHT);
    dim3 gg(32, 64);   // x: N/128, y: M/128
    k_gemm1<<<gg, 256, 0, stream>>>(x, WXTH, WXTL, XZ);
    k_rnn<<<NB, 256, 0, stream>>>(XZ, WHT, b, HROT, FLAGS, out);
}

// Round 5
// 1058.261 us; speedup vs baseline: 1.0383x; 1.0383x over previous
//
#include <hip/hip_runtime.h>
#include <stdint.h>

// Problem: B=64, T=128, F=1024, H=1024. x:[64,128,1024] f32, W:[2048,4096] f32, b:[4096] f32.
// out:[64,128,1024] f32.
#define BATCH 64
#define TSEQ  128
#define FDIM  1024
#define HDIM  1024
#define GDIM  4096              // 4H
#define MROWS 8192              // BATCH*TSEQ
#define NB    128               // persistent blocks in recurrent phase (co-resident on 256 CUs)

typedef short bf16x8 __attribute__((ext_vector_type(8)));   // 8 bf16 in 4 VGPRs
typedef float f32x4  __attribute__((ext_vector_type(4)));

__device__ __forceinline__ unsigned short f2bf(float f) {
    union { float f; uint32_t u; } v; v.f = f;
    uint32_t u = v.u;
    return (unsigned short)((u + 0x7FFFu + ((u >> 16) & 1u)) >> 16);  // RNE
}
__device__ __forceinline__ float bf2f(unsigned short h) {
    union { uint32_t u; float f; } v; v.u = ((uint32_t)h) << 16; return v.f;
}
__device__ __forceinline__ float sigmoidf_(float x) { return 1.f / (1.f + __expf(-x)); }
__device__ __forceinline__ float tanhf_(float x)    { return 2.f / (1.f + __expf(-2.f * x)) - 1.f; }

union SP { short s[8]; int4 v; };
union UU { int4 i; bf16x8 v; };

// L2-bypass 8B store (relaxed agent atomic -> global_store_dwordx2 sc0 sc1, lands at IF).
__device__ __forceinline__ void st64cc(void* p, unsigned long long v) {
    __hip_atomic_store((unsigned long long*)p, v, __ATOMIC_RELAXED, __HIP_MEMORY_SCOPE_AGENT);
}
// L2-bypass 4B store (flag signal).
__device__ __forceinline__ void st32cc(void* p, uint32_t v) {
    __hip_atomic_store((uint32_t*)p, v, __ATOMIC_RELAXED, __HIP_MEMORY_SCOPE_AGENT);
}

// ---------------- init: zero flags + h slot 0 ----------------
__global__ void k_init(uint32_t* p, int nwords) {
    int i = blockIdx.x * blockDim.x + threadIdx.x;
    int s = gridDim.x * blockDim.x;
    for (; i < nwords; i += s) p[i] = 0;
}

// ---------------- W fp32 [2048][4096] -> WxT hi/lo bf16 [4096][1024], WhT bf16 [4096][1024] ----
__global__ void k_tw(const float* __restrict__ W,
                     unsigned short* __restrict__ wxth, unsigned short* __restrict__ wxtl,
                     unsigned short* __restrict__ wht) {
    __shared__ float tile[64 * 65];
    const int nb = blockIdx.x;      // 0..63  (n tiles)
    const int kb = blockIdx.y;      // 0..31  (k tiles over 2048)
    const int t  = threadIdx.x;
    const int col = t & 63, rg = t >> 6;
#pragma unroll
    for (int i = 0; i < 16; i++) {
        int row = rg * 16 + i;
        tile[row * 65 + col] = W[(size_t)(kb * 64 + row) * 4096 + nb * 64 + col];
    }
    __syncthreads();
    if (kb < 16) {
        const int kbase = kb * 64;
#pragma unroll
        for (int i = 0; i < 16; i++) {
            int rp = rg * 16 + i;                      // n index within tile
            float v = tile[col * 65 + rp];             // = W[kb*64+col][nb*64+rp]
            unsigned short h = f2bf(v);
            size_t idx = (size_t)(nb * 64 + rp) * 1024 + kbase + col;
            wxth[idx] = h;
            wxtl[idx] = f2bf(v - bf2f(h));
        }
    } else {
        const int kbase = (kb - 16) * 64;
#pragma unroll
        for (int i = 0; i < 16; i++) {
            int rp = rg * 16 + i;
            float v = tile[col * 65 + rp];
            wht[(size_t)(nb * 64 + rp) * 1024 + kbase + col] = f2bf(v);
        }
    }
}

// ---------------- GEMM1: xz_f32[8192][4096] = x[8192][1024] @ Wx, split-bf16 (3-MFMA) ---------
__global__ __launch_bounds__(256) void k_gemm1(const float* __restrict__ Xf,
                                               const unsigned short* __restrict__ WxTh,
                                               const unsigned short* __restrict__ WxTl,
                                               float* __restrict__ xz) {
    __shared__ short Ash[128 * 40];   // stride 40 elems (80B) -> 2-way banks (free)
    __shared__ short Asl[128 * 40];
    __shared__ short Bsh[128 * 40];
    __shared__ short Bsl[128 * 40];
    const int n0 = blockIdx.x * 128;
    const int m0 = blockIdx.y * 128;
    const int t = threadIdx.x;
    const int wave = t >> 6, lane = t & 63;
    const int wm = wave >> 1, wn = wave & 1;
    const int q = lane >> 4, cl = lane & 15;
    const int row_a = t >> 2;            // 0..63
    const int kc = (t & 3) * 8;          // 8-elem chunk within the 32-elem k-slab

    f32x4 acc[4][4];
#pragma unroll
    for (int i = 0; i < 4; i++)
#pragma unroll
        for (int j = 0; j < 4; j++) acc[i][j] = (f32x4){0.f, 0.f, 0.f, 0.f};

    for (int kb = 0; kb < 32; kb++) {
        const int k0 = kb * 32;
        float va0[8], va1[8];
        {
            const float* p0 = Xf + (size_t)(m0 + row_a) * 1024 + k0 + kc;
            const float* p1 = Xf + (size_t)(m0 + 64 + row_a) * 1024 + k0 + kc;
            *(float4*)(va0)     = *(const float4*)(p0);
            *(float4*)(va0 + 4) = *(const float4*)(p0 + 4);
            *(float4*)(va1)     = *(const float4*)(p1);
            *(float4*)(va1 + 4) = *(const float4*)(p1 + 4);
        }
        int4 bh0 = *(const int4*)(WxTh + (size_t)(n0 + row_a)      * 1024 + k0 + kc);
        int4 bh1 = *(const int4*)(WxTh + (size_t)(n0 + 64 + row_a) * 1024 + k0 + kc);
        int4 bl0 = *(const int4*)(WxTl + (size_t)(n0 + row_a)      * 1024 + k0 + kc);
        int4 bl1 = *(const int4*)(WxTl + (size_t)(n0 + 64 + row_a) * 1024 + k0 + kc);
        __syncthreads();
        {
            SP h0, l0, h1, l1;
#pragma unroll
            for (int i = 0; i < 8; i++) {
                unsigned short h = f2bf(va0[i]);
                h0.s[i] = (short)h; l0.s[i] = (short)f2bf(va0[i] - bf2f(h));
                unsigned short g = f2bf(va1[i]);
                h1.s[i] = (short)g; l1.s[i] = (short)f2bf(va1[i] - bf2f(g));
            }
            *(int4*)(Ash + row_a * 40 + kc)        = h0.v;
            *(int4*)(Asl + row_a * 40 + kc)        = l0.v;
            *(int4*)(Ash + (64 + row_a) * 40 + kc) = h1.v;
            *(int4*)(Asl + (64 + row_a) * 40 + kc) = l1.v;
        }
        *(int4*)(Bsh + row_a * 40 + kc)        = bh0;
        *(int4*)(Bsh + (64 + row_a) * 40 + kc) = bh1;
        *(int4*)(Bsl + row_a * 40 + kc)        = bl0;
        *(int4*)(Bsl + (64 + row_a) * 40 + kc) = bl1;
        __syncthreads();
        bf16x8 ah[4], al[4], bh[4], bl[4];
#pragma unroll
        for (int i = 0; i < 4; i++) {
            ah[i] = *(const bf16x8*)(Ash + (wm * 64 + i * 16 + cl) * 40 + q * 8);
            al[i] = *(const bf16x8*)(Asl + (wm * 64 + i * 16 + cl) * 40 + q * 8);
        }
#pragma unroll
        for (int j = 0; j < 4; j++) {
            bh[j] = *(const bf16x8*)(Bsh + (wn * 64 + j * 16 + cl) * 40 + q * 8);
            bl[j] = *(const bf16x8*)(Bsl + (wn * 64 + j * 16 + cl) * 40 + q * 8);
        }
#pragma unroll
        for (int i = 0; i < 4; i++)
#pragma unroll
            for (int j = 0; j < 4; j++) {
                acc[i][j] = __builtin_amdgcn_mfma_f32_16x16x32_bf16(ah[i], bh[j], acc[i][j], 0, 0, 0);
                acc[i][j] = __builtin_amdgcn_mfma_f32_16x16x32_bf16(al[i], bh[j], acc[i][j], 0, 0, 0);
                acc[i][j] = __builtin_amdgcn_mfma_f32_16x16x32_bf16(ah[i], bl[j], acc[i][j], 0, 0, 0);
            }
    }
    // epilogue: C/D layout col=lane&15, row=q*4+reg; write fp32
#pragma unroll
    for (int i = 0; i < 4; i++) {
#pragma unroll
        for (int j = 0; j < 4; j++) {
            int gm = m0 + wm * 64 + i * 16 + q * 4;
            int gn = n0 + wn * 64 + j * 16 + cl;
#pragma unroll
            for (int r = 0; r < 4; r++)
                xz[(size_t)(gm + r) * 4096 + gn] = acc[i][j][r];
        }
    }
}

// ---------------- persistent recurrent kernel ----------------
// NB=128 blocks x 256 thr (4 waves, 1/SIMD). Block owns 8 h-cols -> 32 gate cols
// [i(8) j(8) | f(8) o(8)]. h exchange: ROTATING buffer (write-once addresses);
// producers bypass-store to IF, consumers normal cached loads. Signal: distributed
// per-producer write-once flags, full-barrier poll (round-2 structure).
// THIS ROUND: B (Wh slice) lives ENTIRELY in 256 VGPRs (2 n-tiles x 32 k-steps x
// bf16x8), loaded once from WhT before the time loop. The 64KB Ws LDS buffer and its
// 512 ds_read_b128/CU/step (~6-7k cy of LDS pipe + conflicts, the dominant serial
// term) are deleted. At 4 waves/block = 1 wave/SIMD, up to 512 VGPR/wave available.
__global__ __launch_bounds__(256, 1) void k_rnn(const float* __restrict__ xz,
                                                const unsigned short* __restrict__ WhT,
                                                const float* __restrict__ bias,
                                                unsigned short* hrot,       // 129 x [64][1024] bf16
                                                int* flags,                 // TSEQ x NB ints, write-once
                                                float* __restrict__ out) {
    __shared__ short hs[64 * 8];        // h transpose staging, 1 KB (only LDS left)
    const int t = threadIdx.x;
    const int blk = blockIdx.x;
    // XCD-grouped columns: blocks blk&7==x own cols [x*128, x*128+128)
    const int n0 = (((blk & 7) << 4) | (blk >> 3)) * 8;
    const int wave = t >> 6, lane = t & 63;
    const int q = lane >> 4, cl = lane & 15;
    const int m = wave * 16 + cl;       // A-fragment row (batch)

    const int cc = cl & 7;
    const bool act = (cl < 8);
    float bi = 0.f, bj = 0.f, bfv = 0.f, bo = 0.f;
    if (act) {
        bi  = bias[n0 + cc];
        bj  = bias[1024 + n0 + cc];
        bfv = bias[2048 + n0 + cc];
        bo  = bias[3072 + n0 + cc];
    }

    // B preload: lane (q,cl) holds, for every k-step kb:
    //   B0[kb] = WhT[(cl>>3)*1024   + n0 + (cl&7)][kb*32+q*8 .. +8]   (gates i,j)
    //   B1[kb] = WhT[(2+(cl>>3))*1024 + n0 + (cl&7)][kb*32+q*8 .. +8] (gates f,o)
    // Same values the old Ws-swizzle ds_reads produced; verified chunk algebra:
    // stored (kch^swl), read (kb*4+q)^sw with sw==swl -> kch = kb*4+q.
    bf16x8 B0[32], B1[32];
    {
        const unsigned short* bsrc0 =
            WhT + (size_t)((cl >> 3) * 1024 + n0 + (cl & 7)) * 1024 + q * 8;
        const unsigned short* bsrc1 =
            WhT + (size_t)((2 + (cl >> 3)) * 1024 + n0 + (cl & 7)) * 1024 + q * 8;
#pragma unroll
        for (int kb = 0; kb < 32; kb++) {
            UU u0, u1;
            u0.i = *(const int4*)(bsrc0 + kb * 32);
            u1.i = *(const int4*)(bsrc1 + kb * 32);
            B0[kb] = u0.v;
            B1[kb] = u1.v;
        }
    }

    float c[4] = {0.f, 0.f, 0.f, 0.f};
    // wave-0..3 poll: lane l covers flag words 2l,2l+1; own flag OR'd in locally.
    const unsigned long long selfmask =
        ((t & 63) == (blk >> 1)) ? ((blk & 1) ? (1ULL << 32) : 1ULL) : 0ULL;

    for (int tt = 0; tt < TSEQ; tt++) {
        // prefetch xz for this step (independent of other blocks' h) — ISSUE BEFORE the spin
        float pxi[4], pxj[4], pxf[4], pxo[4];
        if (act) {
#pragma unroll
            for (int r = 0; r < 4; r++) {
                int m2 = wave * 16 + q * 4 + r;
                const float* xp = xz + (size_t)(m2 * 128 + tt) * 4096 + n0 + cc;
                pxi[r] = xp[0];
                pxj[r] = xp[1024];
                pxf[r] = xp[2048];
                pxo[r] = xp[3072];
            }
        }
        __builtin_amdgcn_sched_barrier(0);   // pin: prefetch issued before poll
        if (tt > 0) {
            if (t < 64) {
                const unsigned long long* fp =
                    (const unsigned long long*)flags + (size_t)(tt - 1) * 64 + t;
                unsigned long long v;
                do {
                    v = __hip_atomic_load(fp, __ATOMIC_RELAXED, __HIP_MEMORY_SCOPE_AGENT);
                } while (!__all((v | selfmask) == 0x0000000100000001ULL));
            }
            __syncthreads();
        }
        // burst-load the FULL h row-slice (32 x int4 = 128 VGPRs), all in flight at once.
        // Addresses write-once => normal cached loads safe.
        const char* ab = (const char*)hrot + (size_t)tt * 131072 + (size_t)m * 2048 + q * 16;
        UU aa[32];
#pragma unroll
        for (int kb = 0; kb < 32; kb++) aa[kb].i = *(const int4*)(ab + kb * 64);
        __builtin_amdgcn_sched_barrier(0);   // pin: burst stays a burst

        f32x4 acc0a = (f32x4){0.f, 0.f, 0.f, 0.f};
        f32x4 acc0b = (f32x4){0.f, 0.f, 0.f, 0.f};
        f32x4 acc1a = (f32x4){0.f, 0.f, 0.f, 0.f};
        f32x4 acc1b = (f32x4){0.f, 0.f, 0.f, 0.f};
#pragma unroll
        for (int kb = 0; kb < 32; kb += 2) {
            acc0a = __builtin_amdgcn_mfma_f32_16x16x32_bf16(aa[kb].v,     B0[kb],     acc0a, 0, 0, 0);
            acc1a = __builtin_amdgcn_mfma_f32_16x16x32_bf16(aa[kb].v,     B1[kb],     acc1a, 0, 0, 0);
            acc0b = __builtin_amdgcn_mfma_f32_16x16x32_bf16(aa[kb + 1].v, B0[kb + 1], acc0b, 0, 0, 0);
            acc1b = __builtin_amdgcn_mfma_f32_16x16x32_bf16(aa[kb + 1].v, B1[kb + 1], acc1b, 0, 0, 0);
        }
        f32x4 acc0 = acc0a + acc0b;
        f32x4 acc1 = acc1a + acc1b;
        // gate math: lane (q,cl<8) row-group q*4+r, col cc; zj/zo live in lane^8
        float zi[4], zj[4], zf[4], zo[4];
#pragma unroll
        for (int r = 0; r < 4; r++) {
            float a0 = acc0[r], a1 = acc1[r];
            float a0x = __shfl_xor(a0, 8);
            float a1x = __shfl_xor(a1, 8);
            zi[r] = a0; zj[r] = a0x; zf[r] = a1; zo[r] = a1x;
        }
        float hv4[4];
        if (act) {
#pragma unroll
            for (int r = 0; r < 4; r++) {
                float vi = zi[r] + pxi[r] + bi;
                float vj = zj[r] + pxj[r] + bj;
                float vf = zf[r] + pxf[r] + bfv + 1.0f;    // forget bias
                float vo = zo[r] + pxo[r] + bo;
                float cn = c[r] * sigmoidf_(vf) + sigmoidf_(vi) * tanhf_(vj);
                c[r] = cn;
                float h = tanhf_(cn) * sigmoidf_(vo);
                hv4[r] = h;
                hs[(wave * 16 + q * 4 + r) * 8 + cc] = (short)f2bf(h);
            }
        }
        __syncthreads();   // hs visible to all waves
        if (t < 128) {
            // row = t>>1 (0..63), half = t&1; 8B per store
            unsigned long long hv = *(const unsigned long long*)(hs + (t >> 1) * 8 + (t & 1) * 4);
            st64cc((char*)hrot + (size_t)(tt + 1) * 131072 + (size_t)(t >> 1) * 2048 + n0 * 2 + (t & 1) * 8, hv);
        }
        __syncthreads();   // vmcnt(0): h row-stores ACK'd at IF before signal
        if (t == 0) st32cc(flags + (size_t)tt * NB + blk, 1u);
        // out stores AFTER the signal — off the pre-signal drain critical path
        if (act) {
#pragma unroll
            for (int r = 0; r < 4; r++) {
                int m2 = wave * 16 + q * 4 + r;
                out[(size_t)(m2 * 128 + tt) * 1024 + n0 + cc] = hv4[r];
            }
        }
    }
}

// ---------------- launch ----------------
extern "C" void kernel_launch(void* const* d_in, const int* in_sizes, int n_in,
                              void* d_out, int out_size, void* d_ws, size_t ws_size,
                              hipStream_t stream) {
    const float* x = (const float*)d_in[0];
    const float* W = (const float*)d_in[1];
    const float* b = (const float*)d_in[2];
    float* out = (float*)d_out;
    char* ws = (char*)d_ws;

    // workspace layout (bytes):
    unsigned short* WXTH = (unsigned short*)(ws);                              // 8 MB
    unsigned short* WXTL = (unsigned short*)(ws + (size_t)8  * 1024 * 1024);   // 8 MB
    unsigned short* WHT  = (unsigned short*)(ws + (size_t)16 * 1024 * 1024);   // 8 MB
    float*          XZ   = (float*)         (ws + (size_t)24 * 1024 * 1024);   // 128 MB fp32
    int*            FLAGS= (int*)           (ws + (size_t)152 * 1024 * 1024);  // 64 KB (TSEQ*NB)
    unsigned short* HROT = (unsigned short*)(ws + (size_t)152 * 1024 * 1024 + 65536); // 129*128KB

    // zero FLAGS (64 KB) + HROT slot 0 (128 KB) = 196608 B = 49152 words
    k_init<<<256, 256, 0, stream>>>((uint32_t*)FLAGS, 49152);
    dim3 gtw(64, 32);
    k_tw<<<gtw, 256, 0, stream>>>(W, WXTH, WXTL, WHT);
    dim3 gg(32, 64);   // x: N/128, y: M/128
    k_gemm1<<<gg, 256, 0, stream>>>(x, WXTH, WXTL, XZ);
    k_rnn<<<NB, 256, 0, stream>>>(XZ, WHT, b, HROT, FLAGS, out);
}